// Round 11
// baseline (115.666 us; speedup 1.0000x reference)
//
#include <hip/hip_runtime.h>
#include <hip/hip_bf16.h>

#define T 50
#define NB 64
#define NS 512
#define START_TAG 48
#define STOP_TAG 49

typedef _Float16 f16_t;
typedef _Float16 f16x2 __attribute__((ext_vector_type(2)));
typedef _Float16 f16x4 __attribute__((ext_vector_type(4)));
typedef float    f32x4 __attribute__((ext_vector_type(4)));

static constexpr float LOG2E = 1.4426950408889634f;
static constexpr float LN2F  = 0.6931471805599453f;
static constexpr float S_E   = 6.0f;     // static log2 shift folded out of E
#define NEG_BIG (-1.0e38f)

__device__ __forceinline__ float fexp2(float x) { return __builtin_amdgcn_exp2f(x); }
__device__ __forceinline__ float flog2(float x) { return __builtin_amdgcn_logf(x); }
__device__ __forceinline__ f16x2 bcast_h2(f16x2 v, int src) {
    unsigned u = __builtin_amdgcn_readlane(__builtin_bit_cast(unsigned, v), src);
    return __builtin_bit_cast(f16x2, u);
}
__device__ __forceinline__ f16x2 pack_h2(float a, float b) {
    return __builtin_bit_cast(f16x2, __builtin_amdgcn_cvt_pkrtz(a, b));
}

// Full-wave (64-lane) fmax via DPP (VALU pipe) -> uniform value via lane 63.
__device__ __forceinline__ float wave_fmax_dpp(float x) {
#define DPP_STEP(ctrl)                                                        \
    do {                                                                      \
        int _s = __builtin_bit_cast(int, x);                                  \
        int _p = __builtin_amdgcn_update_dpp(_s, _s, (ctrl), 0xf, 0xf, false);\
        x = fmaxf(x, __builtin_bit_cast(float, _p));                          \
    } while (0)
    DPP_STEP(0x111);  // row_shr:1
    DPP_STEP(0x112);  // row_shr:2
    DPP_STEP(0x114);  // row_shr:4
    DPP_STEP(0x118);  // row_shr:8
    DPP_STEP(0x142);  // row_bcast:15
    DPP_STEP(0x143);  // row_bcast:31
#undef DPP_STEP
    return __builtin_bit_cast(float,
        __builtin_amdgcn_readlane(__builtin_bit_cast(int, x), 63));
}

// =====================================================================
// Kernel 1 (register-resident, column-sliced, 8 waves/SIMD): 4 waves per
// (batch,chunk). M = C^T; wave w owns M columns [16w,16w+16) in regs
// (Bt[rb], 8 VGPRs). Step: acc[mb] = sum_kb A(mb,kb) x Bt[kb] (16 MFMAs),
// row-scale by cs*descale (f32, exact pow2), RNE f16 back to Bt.
// mfma_f32_16x16x16f16 D-layout == B-layout (HW-verified r8/r9).
// vs round 10:
//  - __launch_bounds__(256,8): 64 VGPR/wave -> 8 blocks/CU resident
//    (LDS 17.9KB x 8 = 143KB < 160KB). 8 waves/SIMD fill the ~27%
//    dependent-chain stall seen at 4 waves (r10 PMC: wall 3300cy/step
//    vs busy 2400).
//  - cs double-buffer DROPPED (r10 A/B: zero effect; frees 16 VGPRs so
//    acc stays in arch VGPRs at the 64-reg budget; Afrag lives in AGPRs
//    where MFMA reads it directly - r10's VGPR=52 confirms).
// =====================================================================
template<int NCHT, int CHLT>
__global__ __launch_bounds__(256, 8)
void crf_chunk(const float* __restrict__ feats, const int* __restrict__ mask,
               const float* __restrict__ trans, f16_t* __restrict__ wsCt,
               float* __restrict__ wsD) {
    const int c    = blockIdx.x;          // chunk
    const int b    = blockIdx.y;          // batch
    const int tid  = threadIdx.x;
    const int w    = tid >> 6;            // wave = column-slice owner
    const int lane = tid & 63;
    const int l15  = lane & 15;
    const int q    = lane >> 4;

    __shared__ float sF[CHLT][64];        // 2^(f_t*log2e) per step / M-row
    __shared__ f16_t Ml[64 * 72];         // epilogue transpose (16B-aligned rows)

    const int t0  = c * CHLT + 1;
    const int nst = (NS - t0 < CHLT) ? (NS - t0) : CHLT;

    // ---- A-const: E^T tiles. A(mb,kb) elem j = E[16kb+4q+j][16mb+l15]
    f16x4 Afrag[4][4];
    #pragma unroll
    for (int mb = 0; mb < 4; mb++)
        #pragma unroll
        for (int kb = 0; kb < 4; kb++) {
            f16x4 v;
            #pragma unroll
            for (int j = 0; j < 4; j++) {
                const int kk = 16 * kb + 4 * q + j;   // row of E
                const int mm = 16 * mb + l15;         // col of E
                float x = 0.f;
                if (kk < T && mm < T) x = fexp2(fmaf(trans[kk * T + mm], LOG2E, -S_E));
                v[j] = (f16_t)x;
            }
            Afrag[mb][kb] = v;
        }

    // ---- preload sF (exp2 once); 4 waves stripe the rows
    for (int r = w; r < CHLT; r += 4) {
        int tl = t0 + r; tl = tl < NS ? tl : NS - 1;
        float fv = (lane < T && r < nst) ? feats[((size_t)b * NS + tl) * T + lane] : 0.f;
        sF[r][lane] = (lane < T && r < nst) ? fexp2(fv * LOG2E) : 0.f;
    }

    // ---- mask bitmap (one ballot; per-step test is SALU)
    unsigned long long bm;
    {
        int tl = t0 + lane; tl = tl < NS ? tl : NS - 1;
        int mv = (lane < nst) ? mask[b * NS + tl] : 0;
        bm = __ballot(mv != 0);
    }
    __syncthreads();                      // sF visible to all waves

    // ---- init wave's slice of M = I: tile rb is I-block (rb, w)
    f16x4 Bt[4];
    #pragma unroll
    for (int rb = 0; rb < 4; rb++) {
        f16x4 v;
        #pragma unroll
        for (int j = 0; j < 4; j++)
            v[j] = (f16_t)((rb == w && 4 * q + j == l15) ? 1.f : 0.f);
        Bt[rb] = v;
    }

    float D  = 0.f;
    float m1 = 1.f, m2 = 1.f;             // wave max from s-1, s-2 (delayed renorm)

    for (int s = 0; s < nst; s++) {
        if ((bm >> s) & 1ull) {
            // cs loads issue first (latency hidden by 8-wave TLP + MFMA below)
            f32x4 cs[4];
            #pragma unroll
            for (int mb = 0; mb < 4; mb++)
                cs[mb] = *(const f32x4*)&sF[s][16 * mb + 4 * q];

            // descale from max TWO doit-steps back (exact pow2; D compensates)
            int ebits = (int)((__float_as_uint(m2) >> 23) & 255) - 127;
            ebits = ebits > 14 ? 14 : (ebits < -14 ? -14 : ebits);
            const float descale = __uint_as_float((unsigned)(127 - ebits) << 23);
            D += (float)ebits + S_E;

            // 16 MFMAs: 4 independent depth-4 accumulate chains
            const f32x4 zz = {0.f, 0.f, 0.f, 0.f};
            f32x4 acc[4];
            #pragma unroll
            for (int mb = 0; mb < 4; mb++)
                acc[mb] = __builtin_amdgcn_mfma_f32_16x16x16f16(Afrag[mb][0], Bt[0], zz, 0, 0, 0);
            #pragma unroll
            for (int kb = 1; kb < 4; kb++)
                #pragma unroll
                for (int mb = 0; mb < 4; mb++)
                    acc[mb] = __builtin_amdgcn_mfma_f32_16x16x16f16(Afrag[mb][kb], Bt[kb], acc[mb], 0, 0, 0);

            // csd = cs*descale (exact pow2 fold), scale, track max, RNE f16
            float wm = 0.f;
            #pragma unroll
            for (int mb = 0; mb < 4; mb++) {
                f32x4 csd;
                #pragma unroll
                for (int r = 0; r < 4; r++) csd[r] = cs[mb][r] * descale;
                float v0 = acc[mb][0] * csd[0];
                float v1 = acc[mb][1] * csd[1];
                float v2 = acc[mb][2] * csd[2];
                float v3 = acc[mb][3] * csd[3];
                wm = fmaxf(wm, fmaxf(fmaxf(v0, v1), fmaxf(v2, v3)));
                f16x4 hv;
                hv[0] = (f16_t)v0; hv[1] = (f16_t)v1;   // RNE, matches prior rounds
                hv[2] = (f16_t)v2; hv[3] = (f16_t)v3;
                Bt[mb] = hv;       // D-layout == B-layout: feeds next step directly
            }

            m2 = m1;
            m1 = wave_fmax_dpp(wm);        // consumed two steps later
        }
    }

    // ---- epilogue: waves dump tiles -> barrier -> coalesced store
    {
        const int P2 = 72;
        #pragma unroll
        for (int rb = 0; rb < 4; rb++) {
            f16x4 v = Bt[rb];
            #pragma unroll
            for (int r = 0; r < 4; r++)
                Ml[(16 * rb + 4 * q + r) * P2 + 16 * w + l15] = v[r];
        }
        __syncthreads();
        // wsCt row j = M row j = column j of C (combine lane j's layout)
        const int row = tid >> 2;          // 0..63
        const int seg = tid & 3;           // 32 B segment
        const f16_t* src = &Ml[row * P2 + seg * 16];
        f16_t* dst = wsCt + ((size_t)(b * NCHT + c)) * 4096 + row * 64 + seg * 16;
        ((int4*)dst)[0] = *(const int4*)&src[0];
        ((int4*)dst)[1] = *(const int4*)&src[8];
    }
    if (lane == 0) wsD[(b * NCHT + c) * 4 + w] = D;   // per-wave (per-16-C-rows) shift
}

// =====================================================================
// Kernel 2 (unchanged from round 10): 2 waves per batch. Wave 0: part-
// chain over NCHT chunk matrices (lane j holds column j of C, 128 B
// contiguous, double-buffered bufA/bufB). Wave 1: gold score.
// Dq[lane>>4] absorbs the per-wave renorm.
// =====================================================================
template<int NCHT>
__global__ __launch_bounds__(128, 1)
void crf_combine(const float* __restrict__ feats, const int* __restrict__ mask,
                 const int* __restrict__ tags, const float* __restrict__ trans,
                 const f16_t* __restrict__ wsCt, const float* __restrict__ wsD,
                 float* __restrict__ out) {
    const int b    = blockIdx.x;
    const int tid  = threadIdx.x;
    const int wv   = tid >> 6;
    const int lane = tid & 63;

    __shared__ float sGold;
    float fwd = 0.f;

    if (wv == 1) {
        float gsum = 0.f;
        int   lcnt = 0;
        for (int s = lane; s < NS; s += 64) {
            int   m  = mask[b * NS + s];
            int   tg = tags[b * NS + s];
            int   pv = (s == 0) ? START_TAG : tags[b * NS + s - 1];
            float e  = feats[((size_t)b * NS + s) * T + tg];
            float tr = trans[pv * T + tg];
            if (m) { gsum += e + tr; lcnt += 1; }
        }
        #pragma unroll
        for (int off = 32; off > 0; off >>= 1) {
            gsum += __shfl_down(gsum, off, 64);
            lcnt += __shfl_down(lcnt, off, 64);
        }
        if (lane == 0) sGold = gsum + trans[tags[b * NS + lcnt - 1] * T + STOP_TAG];
    } else {
        float part = (lane < T)
            ? (feats[(size_t)b * NS * T + lane] + trans[START_TAG * T + lane]) * LOG2E
            : NEG_BIG;

        float Dq[NCHT];
        #pragma unroll
        for (int cc = 0; cc < NCHT; cc++)
            Dq[cc] = wsD[(b * NCHT + cc) * 4 + (lane >> 4)];

        int bufA[32], bufB[32];
        {
            const f16_t* src = wsCt + (size_t)b * NCHT * 4096 + lane * 64;
            #pragma unroll
            for (int kk = 0; kk < 8; kk++)
                *(int4*)&bufA[4 * kk] = ((const int4*)src)[kk];
        }

        auto cbody = [&](int (&cur)[32], int (&nxt)[32], int cc) {
            if (cc + 1 < NCHT) {
                const f16_t* src = wsCt + (size_t)(b * NCHT + cc + 1) * 4096 + lane * 64;
                #pragma unroll
                for (int kk = 0; kk < 8; kk++)
                    *(int4*)&nxt[4 * kk] = ((const int4*)src)[kk];
            }

            float tmp = part + Dq[cc];
            float sft = wave_fmax_dpp(tmp);
            float ex  = fexp2(tmp - sft);
            float exo = __shfl_xor(ex, 1, 64);
            f16x2 pk  = pack_h2(ex, exo);

            float a0 = 0.f, a1 = 0.f, a2 = 0.f, a3 = 0.f;
            #pragma unroll
            for (int k = 0; k < 25; k += 4) {
                a0 = __builtin_amdgcn_fdot2(bcast_h2(pk, 2 * k), __builtin_bit_cast(f16x2, cur[k]), a0, false);
                if (k + 1 < 25) a1 = __builtin_amdgcn_fdot2(bcast_h2(pk, 2 * (k + 1)), __builtin_bit_cast(f16x2, cur[k + 1]), a1, false);
                if (k + 2 < 25) a2 = __builtin_amdgcn_fdot2(bcast_h2(pk, 2 * (k + 2)), __builtin_bit_cast(f16x2, cur[k + 2]), a2, false);
                if (k + 3 < 25) a3 = __builtin_amdgcn_fdot2(bcast_h2(pk, 2 * (k + 3)), __builtin_bit_cast(f16x2, cur[k + 3]), a3, false);
            }
            part = sft + flog2((a0 + a1) + (a2 + a3));
        };

        #pragma unroll
        for (int p = 0; p < NCHT / 2; p++) {
            cbody(bufA, bufB, 2 * p);
            cbody(bufB, bufA, 2 * p + 1);
        }

        float v = (lane < T) ? part + trans[lane * T + STOP_TAG] * LOG2E : NEG_BIG;
        float mx = wave_fmax_dpp(v);
        float ee = (lane < T) ? fexp2(v - mx) : 0.f;
        #pragma unroll
        for (int off = 32; off > 0; off >>= 1) ee += __shfl_xor(ee, off, 64);
        fwd = (mx + flog2(ee)) * LN2F;
    }

    __syncthreads();
    if (tid == 0) atomicAdd(out, fwd - sGold);
}

extern "C" void kernel_launch(void* const* d_in, const int* in_sizes, int n_in,
                              void* d_out, int out_size, void* d_ws, size_t ws_size,
                              hipStream_t stream) {
    const float* feats = (const float*)d_in[0];
    const int*   mask  = (const int*)d_in[1];
    const int*   tags  = (const int*)d_in[2];
    const float* trans = (const float*)d_in[3];
    float* out = (float*)d_out;

    (void)hipMemsetAsync(out, 0, sizeof(float) * out_size, stream);

    const size_t matBytes16 = (size_t)NB * 16 * 4096 * sizeof(f16_t);
    const size_t need16     = matBytes16 + (size_t)NB * 16 * 4 * sizeof(float);

    if (ws_size >= need16) {
        // preferred: 16 chunks x 32 steps, 1024 blocks x 4 waves, 8 blocks/CU
        f16_t* wsCt = (f16_t*)d_ws;
        float* wsD  = (float*)((char*)d_ws + matBytes16);
        crf_chunk<16, 32><<<dim3(16, NB), 256, 0, stream>>>(feats, mask, trans, wsCt, wsD);
        crf_combine<16><<<NB, 128, 0, stream>>>(feats, mask, tags, trans, wsCt, wsD, out);
    } else {
        // fallback: 8 chunks x 64 steps (fits 4.2 MB)
        const size_t matBytes8 = (size_t)NB * 8 * 4096 * sizeof(f16_t);
        f16_t* wsCt = (f16_t*)d_ws;
        float* wsD  = (float*)((char*)d_ws + matBytes8);
        crf_chunk<8, 64><<<dim3(8, NB), 256, 0, stream>>>(feats, mask, trans, wsCt, wsD);
        crf_combine<8><<<NB, 128, 0, stream>>>(feats, mask, tags, trans, wsCt, wsD, out);
    }
}

// Round 12
// 107.307 us; speedup vs baseline: 1.0779x; 1.0779x over previous
//
#include <hip/hip_runtime.h>
#include <hip/hip_bf16.h>

#define T 50
#define NB 64
#define NS 512
#define START_TAG 48
#define STOP_TAG 49

typedef _Float16 f16_t;
typedef _Float16 f16x2 __attribute__((ext_vector_type(2)));
typedef _Float16 f16x4 __attribute__((ext_vector_type(4)));
typedef float    f32x4 __attribute__((ext_vector_type(4)));

static constexpr float LOG2E = 1.4426950408889634f;
static constexpr float LN2F  = 0.6931471805599453f;
static constexpr float S_E   = 6.0f;     // static log2 shift folded out of E
#define NEG_BIG (-1.0e38f)

__device__ __forceinline__ float fexp2(float x) { return __builtin_amdgcn_exp2f(x); }
__device__ __forceinline__ float flog2(float x) { return __builtin_amdgcn_logf(x); }
__device__ __forceinline__ f16x2 bcast_h2(f16x2 v, int src) {
    unsigned u = __builtin_amdgcn_readlane(__builtin_bit_cast(unsigned, v), src);
    return __builtin_bit_cast(f16x2, u);
}
__device__ __forceinline__ f16x2 pack_h2(float a, float b) {
    return __builtin_bit_cast(f16x2, __builtin_amdgcn_cvt_pkrtz(a, b));
}

// Full-wave (64-lane) fmax via DPP (VALU pipe) -> uniform value via lane 63.
__device__ __forceinline__ float wave_fmax_dpp(float x) {
#define DPP_STEP(ctrl)                                                        \
    do {                                                                      \
        int _s = __builtin_bit_cast(int, x);                                  \
        int _p = __builtin_amdgcn_update_dpp(_s, _s, (ctrl), 0xf, 0xf, false);\
        x = fmaxf(x, __builtin_bit_cast(float, _p));                          \
    } while (0)
    DPP_STEP(0x111);  // row_shr:1
    DPP_STEP(0x112);  // row_shr:2
    DPP_STEP(0x114);  // row_shr:4
    DPP_STEP(0x118);  // row_shr:8
    DPP_STEP(0x142);  // row_bcast:15
    DPP_STEP(0x143);  // row_bcast:31
#undef DPP_STEP
    return __builtin_bit_cast(float,
        __builtin_amdgcn_readlane(__builtin_bit_cast(int, x), 63));
}

// =====================================================================
// Kernel 1 (register-resident, column-sliced): 4 waves per (batch,chunk).
// M = C^T; wave w owns M columns [16w,16w+16) in regs (Bt[rb], 8 VGPRs).
// Step: acc[mb] = sum_kb A(mb,kb) x Bt[kb] (16 MFMAs), row-scale by
// cs*descale (f32, exact pow2), RNE f16 back to Bt.
// mfma_f32_16x16x16f16 D-layout == B-layout (HW-verified r8/r9/r10).
// vs rounds 10/11:
//  - __launch_bounds__(256,6): 6 waves/SIMD (reg budget ~85). r10 at 4
//    waves showed 27% step stall (wall 3300cy vs busy 2400); r11 at 8
//    waves (64-reg budget) SPILLED to scratch (FETCH 3.7x, WRITE 3.4x,
//    dur regressed). 6 is the largest occupancy that fits the ~70-reg
//    peak working set.
//  - cs[mb] loaded per-mb INSIDE the scale loop (4 regs live at a time,
//    not 16 up front): r10's A/B proved cs-load placement is latency-
//    neutral, so this only lowers peak register pressure.
// =====================================================================
template<int NCHT, int CHLT>
__global__ __launch_bounds__(256, 6)
void crf_chunk(const float* __restrict__ feats, const int* __restrict__ mask,
               const float* __restrict__ trans, f16_t* __restrict__ wsCt,
               float* __restrict__ wsD) {
    const int c    = blockIdx.x;          // chunk
    const int b    = blockIdx.y;          // batch
    const int tid  = threadIdx.x;
    const int w    = tid >> 6;            // wave = column-slice owner
    const int lane = tid & 63;
    const int l15  = lane & 15;
    const int q    = lane >> 4;

    __shared__ float sF[CHLT][64];        // 2^(f_t*log2e) per step / M-row
    __shared__ f16_t Ml[64 * 72];         // epilogue transpose (16B-aligned rows)

    const int t0  = c * CHLT + 1;
    const int nst = (NS - t0 < CHLT) ? (NS - t0) : CHLT;

    // ---- A-const: E^T tiles. A(mb,kb) elem j = E[16kb+4q+j][16mb+l15]
    f16x4 Afrag[4][4];
    #pragma unroll
    for (int mb = 0; mb < 4; mb++)
        #pragma unroll
        for (int kb = 0; kb < 4; kb++) {
            f16x4 v;
            #pragma unroll
            for (int j = 0; j < 4; j++) {
                const int kk = 16 * kb + 4 * q + j;   // row of E
                const int mm = 16 * mb + l15;         // col of E
                float x = 0.f;
                if (kk < T && mm < T) x = fexp2(fmaf(trans[kk * T + mm], LOG2E, -S_E));
                v[j] = (f16_t)x;
            }
            Afrag[mb][kb] = v;
        }

    // ---- preload sF (exp2 once); 4 waves stripe the rows
    for (int r = w; r < CHLT; r += 4) {
        int tl = t0 + r; tl = tl < NS ? tl : NS - 1;
        float fv = (lane < T && r < nst) ? feats[((size_t)b * NS + tl) * T + lane] : 0.f;
        sF[r][lane] = (lane < T && r < nst) ? fexp2(fv * LOG2E) : 0.f;
    }

    // ---- mask bitmap (one ballot; per-step test is SALU)
    unsigned long long bm;
    {
        int tl = t0 + lane; tl = tl < NS ? tl : NS - 1;
        int mv = (lane < nst) ? mask[b * NS + tl] : 0;
        bm = __ballot(mv != 0);
    }
    __syncthreads();                      // sF visible to all waves

    // ---- init wave's slice of M = I: tile rb is I-block (rb, w)
    f16x4 Bt[4];
    #pragma unroll
    for (int rb = 0; rb < 4; rb++) {
        f16x4 v;
        #pragma unroll
        for (int j = 0; j < 4; j++)
            v[j] = (f16_t)((rb == w && 4 * q + j == l15) ? 1.f : 0.f);
        Bt[rb] = v;
    }

    float D  = 0.f;
    float m1 = 1.f, m2 = 1.f;             // wave max from s-1, s-2 (delayed renorm)

    for (int s = 0; s < nst; s++) {
        if ((bm >> s) & 1ull) {
            // descale from max TWO doit-steps back (exact pow2; D compensates)
            int ebits = (int)((__float_as_uint(m2) >> 23) & 255) - 127;
            ebits = ebits > 14 ? 14 : (ebits < -14 ? -14 : ebits);
            const float descale = __uint_as_float((unsigned)(127 - ebits) << 23);
            D += (float)ebits + S_E;

            // 16 MFMAs: 4 independent depth-4 accumulate chains
            const f32x4 zz = {0.f, 0.f, 0.f, 0.f};
            f32x4 acc[4];
            #pragma unroll
            for (int mb = 0; mb < 4; mb++)
                acc[mb] = __builtin_amdgcn_mfma_f32_16x16x16f16(Afrag[mb][0], Bt[0], zz, 0, 0, 0);
            #pragma unroll
            for (int kb = 1; kb < 4; kb++)
                #pragma unroll
                for (int mb = 0; mb < 4; mb++)
                    acc[mb] = __builtin_amdgcn_mfma_f32_16x16x16f16(Afrag[mb][kb], Bt[kb], acc[mb], 0, 0, 0);

            // per-mb: load cs, fold descale (exact pow2), scale, max, RNE f16
            float wm = 0.f;
            #pragma unroll
            for (int mb = 0; mb < 4; mb++) {
                f32x4 cs = *(const f32x4*)&sF[s][16 * mb + 4 * q];
                f32x4 csd;
                #pragma unroll
                for (int r = 0; r < 4; r++) csd[r] = cs[r] * descale;
                float v0 = acc[mb][0] * csd[0];
                float v1 = acc[mb][1] * csd[1];
                float v2 = acc[mb][2] * csd[2];
                float v3 = acc[mb][3] * csd[3];
                wm = fmaxf(wm, fmaxf(fmaxf(v0, v1), fmaxf(v2, v3)));
                f16x4 hv;
                hv[0] = (f16_t)v0; hv[1] = (f16_t)v1;   // RNE, matches prior rounds
                hv[2] = (f16_t)v2; hv[3] = (f16_t)v3;
                Bt[mb] = hv;       // D-layout == B-layout: feeds next step directly
            }

            m2 = m1;
            m1 = wave_fmax_dpp(wm);        // consumed two steps later
        }
    }

    // ---- epilogue: waves dump tiles -> barrier -> coalesced store
    {
        const int P2 = 72;
        #pragma unroll
        for (int rb = 0; rb < 4; rb++) {
            f16x4 v = Bt[rb];
            #pragma unroll
            for (int r = 0; r < 4; r++)
                Ml[(16 * rb + 4 * q + r) * P2 + 16 * w + l15] = v[r];
        }
        __syncthreads();
        // wsCt row j = M row j = column j of C (combine lane j's layout)
        const int row = tid >> 2;          // 0..63
        const int seg = tid & 3;           // 32 B segment
        const f16_t* src = &Ml[row * P2 + seg * 16];
        f16_t* dst = wsCt + ((size_t)(b * NCHT + c)) * 4096 + row * 64 + seg * 16;
        ((int4*)dst)[0] = *(const int4*)&src[0];
        ((int4*)dst)[1] = *(const int4*)&src[8];
    }
    if (lane == 0) wsD[(b * NCHT + c) * 4 + w] = D;   // per-wave (per-16-C-rows) shift
}

// =====================================================================
// Kernel 2 (unchanged): 2 waves per batch. Wave 0: part-chain over NCHT
// chunk matrices (lane j holds column j of C, 128 B contiguous, double-
// buffered bufA/bufB). Wave 1: gold score. Dq[lane>>4] absorbs the
// per-wave renorm.
// =====================================================================
template<int NCHT>
__global__ __launch_bounds__(128, 1)
void crf_combine(const float* __restrict__ feats, const int* __restrict__ mask,
                 const int* __restrict__ tags, const float* __restrict__ trans,
                 const f16_t* __restrict__ wsCt, const float* __restrict__ wsD,
                 float* __restrict__ out) {
    const int b    = blockIdx.x;
    const int tid  = threadIdx.x;
    const int wv   = tid >> 6;
    const int lane = tid & 63;

    __shared__ float sGold;
    float fwd = 0.f;

    if (wv == 1) {
        float gsum = 0.f;
        int   lcnt = 0;
        for (int s = lane; s < NS; s += 64) {
            int   m  = mask[b * NS + s];
            int   tg = tags[b * NS + s];
            int   pv = (s == 0) ? START_TAG : tags[b * NS + s - 1];
            float e  = feats[((size_t)b * NS + s) * T + tg];
            float tr = trans[pv * T + tg];
            if (m) { gsum += e + tr; lcnt += 1; }
        }
        #pragma unroll
        for (int off = 32; off > 0; off >>= 1) {
            gsum += __shfl_down(gsum, off, 64);
            lcnt += __shfl_down(lcnt, off, 64);
        }
        if (lane == 0) sGold = gsum + trans[tags[b * NS + lcnt - 1] * T + STOP_TAG];
    } else {
        float part = (lane < T)
            ? (feats[(size_t)b * NS * T + lane] + trans[START_TAG * T + lane]) * LOG2E
            : NEG_BIG;

        float Dq[NCHT];
        #pragma unroll
        for (int cc = 0; cc < NCHT; cc++)
            Dq[cc] = wsD[(b * NCHT + cc) * 4 + (lane >> 4)];

        int bufA[32], bufB[32];
        {
            const f16_t* src = wsCt + (size_t)b * NCHT * 4096 + lane * 64;
            #pragma unroll
            for (int kk = 0; kk < 8; kk++)
                *(int4*)&bufA[4 * kk] = ((const int4*)src)[kk];
        }

        auto cbody = [&](int (&cur)[32], int (&nxt)[32], int cc) {
            if (cc + 1 < NCHT) {
                const f16_t* src = wsCt + (size_t)(b * NCHT + cc + 1) * 4096 + lane * 64;
                #pragma unroll
                for (int kk = 0; kk < 8; kk++)
                    *(int4*)&nxt[4 * kk] = ((const int4*)src)[kk];
            }

            float tmp = part + Dq[cc];
            float sft = wave_fmax_dpp(tmp);
            float ex  = fexp2(tmp - sft);
            float exo = __shfl_xor(ex, 1, 64);
            f16x2 pk  = pack_h2(ex, exo);

            float a0 = 0.f, a1 = 0.f, a2 = 0.f, a3 = 0.f;
            #pragma unroll
            for (int k = 0; k < 25; k += 4) {
                a0 = __builtin_amdgcn_fdot2(bcast_h2(pk, 2 * k), __builtin_bit_cast(f16x2, cur[k]), a0, false);
                if (k + 1 < 25) a1 = __builtin_amdgcn_fdot2(bcast_h2(pk, 2 * (k + 1)), __builtin_bit_cast(f16x2, cur[k + 1]), a1, false);
                if (k + 2 < 25) a2 = __builtin_amdgcn_fdot2(bcast_h2(pk, 2 * (k + 2)), __builtin_bit_cast(f16x2, cur[k + 2]), a2, false);
                if (k + 3 < 25) a3 = __builtin_amdgcn_fdot2(bcast_h2(pk, 2 * (k + 3)), __builtin_bit_cast(f16x2, cur[k + 3]), a3, false);
            }
            part = sft + flog2((a0 + a1) + (a2 + a3));
        };

        #pragma unroll
        for (int p = 0; p < NCHT / 2; p++) {
            cbody(bufA, bufB, 2 * p);
            cbody(bufB, bufA, 2 * p + 1);
        }

        float v = (lane < T) ? part + trans[lane * T + STOP_TAG] * LOG2E : NEG_BIG;
        float mx = wave_fmax_dpp(v);
        float ee = (lane < T) ? fexp2(v - mx) : 0.f;
        #pragma unroll
        for (int off = 32; off > 0; off >>= 1) ee += __shfl_xor(ee, off, 64);
        fwd = (mx + flog2(ee)) * LN2F;
    }

    __syncthreads();
    if (tid == 0) atomicAdd(out, fwd - sGold);
}

extern "C" void kernel_launch(void* const* d_in, const int* in_sizes, int n_in,
                              void* d_out, int out_size, void* d_ws, size_t ws_size,
                              hipStream_t stream) {
    const float* feats = (const float*)d_in[0];
    const int*   mask  = (const int*)d_in[1];
    const int*   tags  = (const int*)d_in[2];
    const float* trans = (const float*)d_in[3];
    float* out = (float*)d_out;

    (void)hipMemsetAsync(out, 0, sizeof(float) * out_size, stream);

    const size_t matBytes16 = (size_t)NB * 16 * 4096 * sizeof(f16_t);
    const size_t need16     = matBytes16 + (size_t)NB * 16 * 4 * sizeof(float);

    if (ws_size >= need16) {
        // preferred: 16 chunks x 32 steps, 1024 blocks x 4 waves, 6 blocks/CU
        f16_t* wsCt = (f16_t*)d_ws;
        float* wsD  = (float*)((char*)d_ws + matBytes16);
        crf_chunk<16, 32><<<dim3(16, NB), 256, 0, stream>>>(feats, mask, trans, wsCt, wsD);
        crf_combine<16><<<NB, 128, 0, stream>>>(feats, mask, tags, trans, wsCt, wsD, out);
    } else {
        // fallback: 8 chunks x 64 steps (fits 4.2 MB)
        const size_t matBytes8 = (size_t)NB * 8 * 4096 * sizeof(f16_t);
        f16_t* wsCt = (f16_t*)d_ws;
        float* wsD  = (float*)((char*)d_ws + matBytes8);
        crf_chunk<8, 64><<<dim3(8, NB), 256, 0, stream>>>(feats, mask, trans, wsCt, wsD);
        crf_combine<8><<<NB, 128, 0, stream>>>(feats, mask, tags, trans, wsCt, wsD, out);
    }
}